// Round 1
// baseline (124.013 us; speedup 1.0000x reference)
//
#include <hip/hip_runtime.h>

// Problem constants
#define BB_   16
#define CIN_  32
#define COUT_ 64
#define TT_   20      // depthwise time extent
#define NSTEP 22      // recurrence steps (pointwise pad grows T 20->22)
#define NPIX  1024    // 32*32
#define HW_   32

// ws layout (in floats)
#define N_DWOUT (10485760ULL)                  // 16*32*20*1024
#define N_CONV2 (20971520ULL)                  // 16*64*20*1024
#define OFF_DWOUT 0ULL
#define OFF_CONV2 (OFF_DWOUT + N_DWOUT)
#define OFF_D     (OFF_CONV2 + N_CONV2)        // 4096 floats
#define OFF_INVN  (OFF_D + 4096ULL)            // 64 floats
#define OFF_CNT   (OFF_INVN + 64ULL)           // 22 uint32
#define WS_FLOATS (OFF_CNT + 32ULL)

// ---------------------------------------------------------------------------
// K1: depthwise 3x3x3 conv, per (b, ci, t-quarter). dwout[b][ci][t][h][w]
// ---------------------------------------------------------------------------
__global__ __launch_bounds__(128)
void k_depthwise(const float* __restrict__ x, const float* __restrict__ wdw,
                 float* __restrict__ dwout) {
    const int blk = blockIdx.x;
    const int t4 = blk & 3;
    const int ci = (blk >> 2) & 31;
    const int b  = blk >> 7;
    const int tid = threadIdx.x;
    __shared__ float pl[3][34][35];   // 3 ring slots, padded plane (35 = bank decorrelation)

    float w[27];
#pragma unroll
    for (int k = 0; k < 27; ++k) w[k] = wdw[ci * 27 + k];

    for (int i = tid; i < 3 * 34 * 35; i += 128) (&pl[0][0][0])[i] = 0.f;
    __syncthreads();

    const float* xb = x + (size_t)(b * 32 + ci) * TT_ * NPIX;
    const int lr = tid >> 2;            // 0..31 row
    const int lc = (tid & 3) * 8;       // col group of 8

    auto load_plane = [&](int p, int slot) {
        const float* s = xb + (size_t)p * NPIX + lr * 32 + lc;
        float4 v0 = *(const float4*)s;
        float4 v1 = *(const float4*)(s + 4);
        float* d = &pl[slot][1 + lr][1 + lc];
        d[0] = v0.x; d[1] = v0.y; d[2] = v0.z; d[3] = v0.w;
        d[4] = v1.x; d[5] = v1.y; d[6] = v1.z; d[7] = v1.w;
    };
    auto zero_plane = [&](int slot) {
        float* d = &pl[slot][1 + lr][1 + lc];
#pragma unroll
        for (int j = 0; j < 8; ++j) d[j] = 0.f;
    };

    const int T0 = t4 * 5;
    if (T0 > 0) load_plane(T0 - 1, (T0 - 1) % 3);
    load_plane(T0, T0 % 3);

    const int hd = lr, wd0 = lc;
    const float* base = &pl[0][0][0];

    for (int t = T0; t < T0 + 5; ++t) {
        __syncthreads();                        // prior compute reads done
        const int pnext = t + 1;
        if (pnext < TT_) load_plane(pnext, pnext % 3);
        else             zero_plane(pnext % 3);
        __syncthreads();                        // loads visible

        const int sm1 = (t + 2) % 3, s0 = t % 3, sp1 = (t + 1) % 3;
        float acc[8] = {0.f,0.f,0.f,0.f,0.f,0.f,0.f,0.f};
#pragma unroll
        for (int kt = 0; kt < 3; ++kt) {
            const int slot = (kt == 0) ? sm1 : (kt == 1) ? s0 : sp1;
            const float* Pp = base + slot * (34 * 35);
#pragma unroll
            for (int kh = 0; kh < 3; ++kh) {
                const float* row = Pp + (hd + kh) * 35 + wd0;
                float r[10];
#pragma unroll
                for (int m = 0; m < 10; ++m) r[m] = row[m];
#pragma unroll
                for (int kw = 0; kw < 3; ++kw) {
                    const float wv = w[(kt * 3 + kh) * 3 + kw];
#pragma unroll
                    for (int j = 0; j < 8; ++j) acc[j] = fmaf(wv, r[j + kw], acc[j]);
                }
            }
        }
        float* dst = dwout + ((size_t)(b * 32 + ci) * TT_ + t) * NPIX + hd * 32 + wd0;
        *(float4*)dst       = make_float4(acc[0], acc[1], acc[2], acc[3]);
        *(float4*)(dst + 4) = make_float4(acc[4], acc[5], acc[6], acc[7]);
    }
}

// ---------------------------------------------------------------------------
// K2: lateral matrix d = Wpw diag(S) Wpw^T (fp64), inv_norm = 1/(diag + eps)
// ---------------------------------------------------------------------------
__global__ __launch_bounds__(256)
void k_dmat(const float* __restrict__ wdw, const float* __restrict__ wpw,
            float* __restrict__ dmat, float* __restrict__ invn) {
    __shared__ double S[32];
    const int tid = threadIdx.x;
    if (tid < 32) {
        double s = 0.0;
        for (int k = 0; k < 27; ++k) { double v = (double)wdw[tid * 27 + k]; s += v * v; }
        S[tid] = s;
    }
    __syncthreads();
    for (int e = tid; e < 4096; e += 256) {
        const int a = e >> 6, f = e & 63;
        double acc = 0.0;
        for (int ci = 0; ci < 32; ++ci)
            acc += (double)wpw[a * 32 + ci] * (double)wpw[f * 32 + ci] * S[ci];
        dmat[e] = (float)acc;
        if (a == f) invn[a] = (float)(1.0 / (acc + 1e-8));
    }
}

// ---------------------------------------------------------------------------
// K3: pointwise conv (shifted by pad): conv2[b][co][td][h][w] =
//     sum_ci wpw[co][ci] * dwout[b][ci][td][h-1][w-1]   (zeros at h=0/w=0)
// block = ((b*20 + td)*4 + h8); 8x8 register tiles
// ---------------------------------------------------------------------------
__global__ __launch_bounds__(256)
void k_pointwise(const float* __restrict__ dwout, const float* __restrict__ wpw,
                 float* __restrict__ conv2) {
    int blk = blockIdx.x;
    const int h8 = blk & 3; blk >>= 2;
    const int td = blk % 20;
    const int b  = blk / 20;
    const int tid = threadIdx.x;

    __shared__ float wt[32][64];        // wt[ci][co]
    __shared__ float dwin[32][8][32];   // [ci][row][w] pre-shifted

    for (int i = tid; i < 2048; i += 256) {
        const int ci = i >> 6, co = i & 63;
        wt[ci][co] = wpw[co * 32 + ci];
    }
    for (int i = tid; i < 8192; i += 256) {
        const int ci = i >> 8, r = (i >> 5) & 7, ww = i & 31;
        const int h = h8 * 8 + r;
        float v = 0.f;
        if (h >= 1 && ww >= 1)
            v = dwout[((size_t)(b * 32 + ci) * TT_ + td) * NPIX + (h - 1) * 32 + (ww - 1)];
        dwin[ci][r][ww] = v;
    }
    __syncthreads();

    const int cog = tid >> 5, pxg = tid & 31;
    const int co0 = cog * 8, hl = pxg >> 2, w0 = (pxg & 3) * 8;

    float acc[8][8];
#pragma unroll
    for (int i = 0; i < 8; ++i)
#pragma unroll
        for (int j = 0; j < 8; ++j) acc[i][j] = 0.f;

    for (int ci = 0; ci < 32; ++ci) {
        float4 wa0 = *(const float4*)&wt[ci][co0];
        float4 wa1 = *(const float4*)&wt[ci][co0 + 4];
        float4 vb0 = *(const float4*)&dwin[ci][hl][w0];
        float4 vb1 = *(const float4*)&dwin[ci][hl][w0 + 4];
        const float A[8] = {wa0.x, wa0.y, wa0.z, wa0.w, wa1.x, wa1.y, wa1.z, wa1.w};
        const float Bv[8] = {vb0.x, vb0.y, vb0.z, vb0.w, vb1.x, vb1.y, vb1.z, vb1.w};
#pragma unroll
        for (int i = 0; i < 8; ++i)
#pragma unroll
            for (int j = 0; j < 8; ++j) acc[i][j] = fmaf(A[i], Bv[j], acc[i][j]);
    }

    const int h = h8 * 8 + hl;
#pragma unroll
    for (int i = 0; i < 8; ++i) {
        const int co = co0 + i;
        float* dst = conv2 + ((size_t)(b * 64 + co) * TT_ + td) * NPIX + h * 32 + w0;
        *(float4*)dst       = make_float4(acc[i][0], acc[i][1], acc[i][2], acc[i][3]);
        *(float4*)(dst + 4) = make_float4(acc[i][4], acc[i][5], acc[i][6], acc[i][7]);
    }
}

// ---------------------------------------------------------------------------
// K4: leaky soft-reset recurrence with lateral inhibition via sparse masks.
// block = (b, h); thread = (co, 8 consecutive w). Spikes -> per-pixel bitmask;
// rst = sum of d rows over set bits (bitwise identical to dense fp32 sum).
// ---------------------------------------------------------------------------
__global__ __launch_bounds__(256)
void k_recur(const float* __restrict__ conv2, const float* __restrict__ dmat,
             const float* __restrict__ invn_g, const float* __restrict__ beta_g,
             const float* __restrict__ bvec, float* __restrict__ out,
             unsigned* __restrict__ gcnt) {
    const int b = blockIdx.x >> 5, h = blockIdx.x & 31;
    const int tid = threadIdx.x;
    const int co = tid >> 2, w0 = (tid & 3) * 8;

    __shared__ float d_lds[4096];
    __shared__ unsigned mlo[32], mhi[32];
    __shared__ unsigned cnt_sh;

    for (int i = tid; i < 4096; i += 256) d_lds[i] = dmat[i];
    if (tid < 32) { mlo[tid] = 0u; mhi[tid] = 0u; }
    if (tid == 0) cnt_sh = 0u;

    const float beta_v = beta_g[0];
    const float omb = 1.0f - beta_v;
    const float invn = invn_g[co];
    const float bth  = bvec[co];

    float mem[8];
#pragma unroll
    for (int p = 0; p < 8; ++p) mem[p] = 0.f;
    __syncthreads();

    const size_t cbase = ((size_t)(b * 64 + co) * TT_) * NPIX + h * 32 + w0;
    const size_t obase = ((size_t)(b * 64 + co) * NSTEP) * NPIX + h * 32 + w0;

    for (int t = 0; t < NSTEP; ++t) {
        // lateral reset from previous step's spikes (sparse)
        float rst[8];
#pragma unroll
        for (int p = 0; p < 8; ++p) {
            float r = 0.f;
            unsigned m0 = mlo[w0 + p], m1 = mhi[w0 + p];
            while (m0) { const int a = __builtin_ctz(m0); m0 &= m0 - 1; r += d_lds[(a << 6) + co]; }
            while (m1) { const int a = __builtin_ctz(m1); m1 &= m1 - 1; r += d_lds[((a + 32) << 6) + co]; }
            rst[p] = r;
        }
        // input (pointwise conv output, shifted: valid for t in [1,20])
        float inp[8];
        if (t >= 1 && t <= TT_) {
            const float* src = conv2 + cbase + (size_t)(t - 1) * NPIX;
            float4 v0 = *(const float4*)src, v1 = *(const float4*)(src + 4);
            inp[0]=v0.x; inp[1]=v0.y; inp[2]=v0.z; inp[3]=v0.w;
            inp[4]=v1.x; inp[5]=v1.y; inp[6]=v1.z; inp[7]=v1.w;
        } else {
#pragma unroll
            for (int p = 0; p < 8; ++p) inp[p] = 0.f;
        }
        // membrane update + spike (mirror reference op order in fp32)
        unsigned cnt = 0;
        float spk[8];
#pragma unroll
        for (int p = 0; p < 8; ++p) {
            const float u = (mem[p] - rst[p]) * beta_v;
            mem[p] = u + inp[p] * omb;
            const float v = mem[p] * invn - bth;
            const bool s = v > 0.f;
            spk[p] = s ? 1.f : 0.f;
            cnt += s ? 1u : 0u;
        }
        float* dst = out + obase + (size_t)t * NPIX;
        *(float4*)dst       = make_float4(spk[0], spk[1], spk[2], spk[3]);
        *(float4*)(dst + 4) = make_float4(spk[4], spk[5], spk[6], spk[7]);

        __syncthreads();                 // all mask reads done
        if (tid < 32) { mlo[tid] = 0u; mhi[tid] = 0u; }
        if (tid == 0) cnt_sh = 0u;
        __syncthreads();
        if (cnt) {
#pragma unroll
            for (int p = 0; p < 8; ++p) if (spk[p] > 0.f) {
                if (co < 32) atomicOr(&mlo[w0 + p], 1u << co);
                else         atomicOr(&mhi[w0 + p], 1u << (co - 32));
            }
            atomicAdd(&cnt_sh, cnt);
        }
        __syncthreads();
        if (tid == 0 && cnt_sh) atomicAdd(&gcnt[t], cnt_sh);
    }
}

// ---------------------------------------------------------------------------
// K5: losses from exact integer spike counts
// ---------------------------------------------------------------------------
__global__ void k_final(const unsigned* __restrict__ gcnt, float* __restrict__ out,
                        int out_size) {
    if (threadIdx.x == 0 && blockIdx.x == 0) {
        unsigned long long tot = 0; unsigned mx = 0;
        for (int t = 0; t < NSTEP; ++t) { const unsigned c = gcnt[t]; tot += c; if (c > mx) mx = c; }
        const long long nspk = (long long)out_size - 2;   // 23,068,672
        out[out_size - 2] = (float)(0.5 * ((double)tot / (double)nspk));
        out[out_size - 1] = (float)((double)mx / 65536.0);
    }
}

extern "C" void kernel_launch(void* const* d_in, const int* in_sizes, int n_in,
                              void* d_out, int out_size, void* d_ws, size_t ws_size,
                              hipStream_t stream) {
    const float* x    = (const float*)d_in[0];
    const float* wdw  = (const float*)d_in[1];
    const float* wpw  = (const float*)d_in[2];
    const float* beta = (const float*)d_in[3];
    const float* bvec = (const float*)d_in[4];
    float* out = (float*)d_out;
    float* ws  = (float*)d_ws;

    if (ws_size < WS_FLOATS * sizeof(float)) return;  // insufficient scratch

    float* dwout = ws + OFF_DWOUT;
    float* conv2 = ws + OFF_CONV2;
    float* dmat  = ws + OFF_D;
    float* invn  = ws + OFF_INVN;
    unsigned* gcnt = (unsigned*)(ws + OFF_CNT);

    hipMemsetAsync(gcnt, 0, NSTEP * sizeof(unsigned), stream);

    k_depthwise<<<BB_ * CIN_ * 4, 128, 0, stream>>>(x, wdw, dwout);
    k_dmat     <<<1, 256, 0, stream>>>(wdw, wpw, dmat, invn);
    k_pointwise<<<BB_ * 20 * 4, 256, 0, stream>>>(dwout, wpw, conv2);
    k_recur    <<<BB_ * HW_, 256, 0, stream>>>(conv2, dmat, invn, beta, bvec, out, gcnt);
    k_final    <<<1, 64, 0, stream>>>(gcnt, out, out_size);
}

// Round 2
// 122.049 us; speedup vs baseline: 1.0161x; 1.0161x over previous
//
#include <hip/hip_runtime.h>

// Problem constants
#define BB_   16
#define CIN_  32
#define COUT_ 64
#define TT_   20      // depthwise time extent
#define NSTEP 22      // recurrence steps (pointwise pad grows T 20->22)
#define NPIX  1024    // 32*32
#define HW_   32

typedef float floatx4 __attribute__((ext_vector_type(4)));

// ws layout (in floats)
#define N_DWOUT (10485760ULL)                  // 16*32*20*1024
#define OFF_DWOUT 0ULL
#define OFF_D     (OFF_DWOUT + N_DWOUT)        // 4096 floats
#define OFF_INVN  (OFF_D + 4096ULL)            // 64 floats
#define OFF_CNT   (OFF_INVN + 64ULL)           // 22 uint32
#define WS_FLOATS (OFF_CNT + 32ULL)

// ---------------------------------------------------------------------------
// K1: depthwise 3x3x3 conv, per (b, ci, t-quarter). dwout[b][ci][t][h][w]
// ---------------------------------------------------------------------------
__global__ __launch_bounds__(128)
void k_depthwise(const float* __restrict__ x, const float* __restrict__ wdw,
                 float* __restrict__ dwout) {
    const int blk = blockIdx.x;
    const int t4 = blk & 3;
    const int ci = (blk >> 2) & 31;
    const int b  = blk >> 7;
    const int tid = threadIdx.x;
    __shared__ float pl[3][34][35];

    float w[27];
#pragma unroll
    for (int k = 0; k < 27; ++k) w[k] = wdw[ci * 27 + k];

    for (int i = tid; i < 3 * 34 * 35; i += 128) (&pl[0][0][0])[i] = 0.f;
    __syncthreads();

    const float* xb = x + (size_t)(b * 32 + ci) * TT_ * NPIX;
    const int lr = tid >> 2;            // 0..31 row
    const int lc = (tid & 3) * 8;       // col group of 8

    auto load_plane = [&](int p, int slot) {
        const float* s = xb + (size_t)p * NPIX + lr * 32 + lc;
        float4 v0 = *(const float4*)s;
        float4 v1 = *(const float4*)(s + 4);
        float* d = &pl[slot][1 + lr][1 + lc];
        d[0] = v0.x; d[1] = v0.y; d[2] = v0.z; d[3] = v0.w;
        d[4] = v1.x; d[5] = v1.y; d[6] = v1.z; d[7] = v1.w;
    };
    auto zero_plane = [&](int slot) {
        float* d = &pl[slot][1 + lr][1 + lc];
#pragma unroll
        for (int j = 0; j < 8; ++j) d[j] = 0.f;
    };

    const int T0 = t4 * 5;
    if (T0 > 0) load_plane(T0 - 1, (T0 - 1) % 3);
    load_plane(T0, T0 % 3);

    const int hd = lr, wd0 = lc;
    const float* base = &pl[0][0][0];

    for (int t = T0; t < T0 + 5; ++t) {
        __syncthreads();
        const int pnext = t + 1;
        if (pnext < TT_) load_plane(pnext, pnext % 3);
        else             zero_plane(pnext % 3);
        __syncthreads();

        const int sm1 = (t + 2) % 3, s0 = t % 3, sp1 = (t + 1) % 3;
        float acc[8] = {0.f,0.f,0.f,0.f,0.f,0.f,0.f,0.f};
#pragma unroll
        for (int kt = 0; kt < 3; ++kt) {
            const int slot = (kt == 0) ? sm1 : (kt == 1) ? s0 : sp1;
            const float* Pp = base + slot * (34 * 35);
#pragma unroll
            for (int kh = 0; kh < 3; ++kh) {
                const float* row = Pp + (hd + kh) * 35 + wd0;
                float r[10];
#pragma unroll
                for (int m = 0; m < 10; ++m) r[m] = row[m];
#pragma unroll
                for (int kw = 0; kw < 3; ++kw) {
                    const float wv = w[(kt * 3 + kh) * 3 + kw];
#pragma unroll
                    for (int j = 0; j < 8; ++j) acc[j] = fmaf(wv, r[j + kw], acc[j]);
                }
            }
        }
        float* dst = dwout + ((size_t)(b * 32 + ci) * TT_ + t) * NPIX + hd * 32 + wd0;
        *(float4*)dst       = make_float4(acc[0], acc[1], acc[2], acc[3]);
        *(float4*)(dst + 4) = make_float4(acc[4], acc[5], acc[6], acc[7]);
    }
}

// ---------------------------------------------------------------------------
// K2: lateral matrix d = Wpw diag(S) Wpw^T (fp64), inv_norm; also zeros gcnt
// ---------------------------------------------------------------------------
__global__ __launch_bounds__(256)
void k_dmat(const float* __restrict__ wdw, const float* __restrict__ wpw,
            float* __restrict__ dmat, float* __restrict__ invn,
            unsigned* __restrict__ gcnt) {
    __shared__ double S[32];
    const int tid = threadIdx.x;
    if (tid < NSTEP) gcnt[tid] = 0u;
    if (tid < 32) {
        double s = 0.0;
        for (int k = 0; k < 27; ++k) { double v = (double)wdw[tid * 27 + k]; s += v * v; }
        S[tid] = s;
    }
    __syncthreads();
    for (int e = tid; e < 4096; e += 256) {
        const int a = e >> 6, f = e & 63;
        double acc = 0.0;
        for (int ci = 0; ci < 32; ++ci)
            acc += (double)wpw[a * 32 + ci] * (double)wpw[f * 32 + ci] * S[ci];
        dmat[e] = (float)acc;
        if (a == f) invn[a] = (float)(1.0 / (acc + 1e-8));
    }
}

// ---------------------------------------------------------------------------
// K3': fused pointwise conv + leaky soft-reset recurrence.
// block = (b, h); thread = (co-pair cp, w-quad wq). Per step: stage shifted
// row dwout[b,:,t-1,h-1,:] in LDS (double-buffered, prefetch 1 step ahead),
// inp = sum_ci wpw[co][ci]*dwin[ci][w] (2co x 4w register tile, wpw in VGPRs).
// Spikes -> per-pixel 64-bit masks; lateral reset via sparse bit iteration
// (bitwise identical to dense fp32 sum).
// ---------------------------------------------------------------------------
__global__ __launch_bounds__(256)
void k_recur_fused(const float* __restrict__ dwout, const float* __restrict__ wpw,
                   const float* __restrict__ dmat, const float* __restrict__ invn_g,
                   const float* __restrict__ beta_g, const float* __restrict__ bvec,
                   float* __restrict__ out, unsigned* __restrict__ gcnt) {
    const int b = blockIdx.x >> 5, h = blockIdx.x & 31;
    const int tid = threadIdx.x;
    const int cp = tid >> 3;          // 0..31 co-pair
    const int wq = tid & 7;           // 0..7
    const int w0 = wq * 4;
    const int co0 = cp * 2;

    __shared__ __align__(16) float d_lds[4096];
    __shared__ __align__(16) float dwin[2][32][40];   // [buf][ci][1+w], stride 40: 2-way-max bank
    __shared__ unsigned mlo[32], mhi[32];
    __shared__ unsigned cnt_sh;

    for (int i = tid; i < 4096; i += 256) d_lds[i] = dmat[i];
    {
        float* p = &dwin[0][0][0];
        for (int i = tid; i < 2 * 32 * 40; i += 256) p[i] = 0.f;
    }
    if (tid < 32) { mlo[tid] = 0u; mhi[tid] = 0u; }
    if (tid == 0) cnt_sh = 0u;

    const float beta_v = beta_g[0];
    const float omb = 1.0f - beta_v;
    const float invn0 = invn_g[co0], invn1 = invn_g[co0 + 1];
    const float bth0 = bvec[co0],    bth1 = bvec[co0 + 1];

    // wpw rows for this thread's two channels (64 VGPRs, ci-loop fully unrolled)
    float2 wa[32];
#pragma unroll
    for (int ci = 0; ci < 32; ++ci)
        wa[ci] = make_float2(wpw[co0 * 32 + ci], wpw[(co0 + 1) * 32 + ci]);

    float mem0[4] = {0.f,0.f,0.f,0.f}, mem1[4] = {0.f,0.f,0.f,0.f};

    // t = 0: inp = 0 (time pad), mem stays 0, mthr = -b < 0 -> all spikes zero.
    const size_t ob0 = ((size_t)(b * 64 + co0) * NSTEP) * NPIX + h * 32 + w0;
    const size_t ob1 = ob0 + (size_t)NSTEP * NPIX;
    *(float4*)(out + ob0) = make_float4(0.f, 0.f, 0.f, 0.f);
    *(float4*)(out + ob1) = make_float4(0.f, 0.f, 0.f, 0.f);

    const int sci = cp, seg = wq;     // staging role: ci row, 4-float segment
    const float* srow_base = dwout + ((size_t)(b * 32 + sci) * TT_) * NPIX + (h - 1) * 32;
    const bool hok = (h >= 1);

    __syncthreads();                  // zeroing done before staging writes

    if (hok) {                        // stage row for t=1 (dwout plane 0) into dwin[1]
        float4 g = *(const float4*)(srow_base + seg * 4);
        float* dp = &dwin[1][sci][1 + seg * 4];
        dp[0] = g.x; dp[1] = g.y; dp[2] = g.z; dp[3] = g.w;
    }
    __syncthreads();

    int cur = 1;
    for (int t = 1; t < NSTEP; ++t) {
        // prefetch next row (for step t+1) early: latency hides under compute
        float4 gn;
        const bool pf = (t + 1 <= TT_) && hok;
        if (pf) gn = *(const float4*)(srow_base + (size_t)t * NPIX + seg * 4);

        // lateral reset from previous step's spikes (sparse bit iteration)
        float rst0[4], rst1[4];
#pragma unroll
        for (int p = 0; p < 4; ++p) {
            float r0 = 0.f, r1 = 0.f;
            unsigned m0 = mlo[w0 + p], m1 = mhi[w0 + p];
            while (m0) { const int a = __builtin_ctz(m0); m0 &= m0 - 1;
                const float2 dv = *(const float2*)&d_lds[(a << 6) + co0]; r0 += dv.x; r1 += dv.y; }
            while (m1) { const int a = __builtin_ctz(m1); m1 &= m1 - 1;
                const float2 dv = *(const float2*)&d_lds[((a + 32) << 6) + co0]; r0 += dv.x; r1 += dv.y; }
            rst0[p] = r0; rst1[p] = r1;
        }

        // pointwise conv input (fused): identical fmaf chain to unfused GEMM
        float inp0[4] = {0.f,0.f,0.f,0.f}, inp1[4] = {0.f,0.f,0.f,0.f};
        if (t <= TT_) {
#pragma unroll
            for (int ci = 0; ci < 32; ++ci) {
                const floatx4 bv = *(const floatx4*)&dwin[cur][ci][w0];
                const float ax = wa[ci].x, ay = wa[ci].y;
#pragma unroll
                for (int k = 0; k < 4; ++k) {
                    inp0[k] = fmaf(ax, bv[k], inp0[k]);
                    inp1[k] = fmaf(ay, bv[k], inp1[k]);
                }
            }
        }

        // membrane update + spike (same op order as round-1 pass)
        unsigned cnt = 0;
        float spk0[4], spk1[4];
#pragma unroll
        for (int p = 0; p < 4; ++p) {
            const float u0 = (mem0[p] - rst0[p]) * beta_v;
            mem0[p] = u0 + inp0[p] * omb;
            const bool s0 = (mem0[p] * invn0 - bth0) > 0.f;
            spk0[p] = s0 ? 1.f : 0.f; cnt += s0 ? 1u : 0u;
            const float u1 = (mem1[p] - rst1[p]) * beta_v;
            mem1[p] = u1 + inp1[p] * omb;
            const bool s1 = (mem1[p] * invn1 - bth1) > 0.f;
            spk1[p] = s1 ? 1.f : 0.f; cnt += s1 ? 1u : 0u;
        }
        *(float4*)(out + ob0 + (size_t)t * NPIX) = make_float4(spk0[0], spk0[1], spk0[2], spk0[3]);
        *(float4*)(out + ob1 + (size_t)t * NPIX) = make_float4(spk1[0], spk1[1], spk1[2], spk1[3]);

        __syncthreads();              // B1: mask + dwin[cur] reads complete
        if (pf) {                     // write prefetched row into the other buffer
            float* dp = &dwin[cur ^ 1][sci][1 + seg * 4];
            dp[0] = gn.x; dp[1] = gn.y; dp[2] = gn.z; dp[3] = gn.w;
        }
        if (tid < 32) { mlo[tid] = 0u; mhi[tid] = 0u; }
        if (tid == 0) cnt_sh = 0u;
        __syncthreads();              // B2: zeros visible
        if (cnt) {
#pragma unroll
            for (int p = 0; p < 4; ++p) {
                const unsigned bits = (spk0[p] > 0.f ? 1u : 0u) | (spk1[p] > 0.f ? 2u : 0u);
                if (bits) {
                    unsigned* mp = (cp < 16) ? &mlo[w0 + p] : &mhi[w0 + p];
                    atomicOr(mp, bits << (co0 & 31));
                }
            }
            atomicAdd(&cnt_sh, cnt);
        }
        __syncthreads();              // B3: masks + staged dwin ready for t+1
        if (tid == 0 && cnt_sh) atomicAdd(&gcnt[t], cnt_sh);
        cur ^= 1;
    }
}

// ---------------------------------------------------------------------------
// K4: losses from exact integer spike counts
// ---------------------------------------------------------------------------
__global__ void k_final(const unsigned* __restrict__ gcnt, float* __restrict__ out,
                        int out_size) {
    if (threadIdx.x == 0 && blockIdx.x == 0) {
        unsigned long long tot = 0; unsigned mx = 0;
        for (int t = 0; t < NSTEP; ++t) { const unsigned c = gcnt[t]; tot += c; if (c > mx) mx = c; }
        const long long nspk = (long long)out_size - 2;          // 23,068,672
        out[out_size - 2] = (float)(0.5 * ((double)tot / (double)nspk));
        out[out_size - 1] = (float)((double)mx / 1048576.0);     // / (B*COUT*H*W)
    }
}

extern "C" void kernel_launch(void* const* d_in, const int* in_sizes, int n_in,
                              void* d_out, int out_size, void* d_ws, size_t ws_size,
                              hipStream_t stream) {
    const float* x    = (const float*)d_in[0];
    const float* wdw  = (const float*)d_in[1];
    const float* wpw  = (const float*)d_in[2];
    const float* beta = (const float*)d_in[3];
    const float* bvec = (const float*)d_in[4];
    float* out = (float*)d_out;
    float* ws  = (float*)d_ws;

    if (ws_size < WS_FLOATS * sizeof(float)) return;

    float* dwout = ws + OFF_DWOUT;
    float* dmat  = ws + OFF_D;
    float* invn  = ws + OFF_INVN;
    unsigned* gcnt = (unsigned*)(ws + OFF_CNT);

    k_depthwise  <<<BB_ * CIN_ * 4, 128, 0, stream>>>(x, wdw, dwout);
    k_dmat       <<<1, 256, 0, stream>>>(wdw, wpw, dmat, invn, gcnt);
    k_recur_fused<<<BB_ * HW_, 256, 0, stream>>>(dwout, wpw, dmat, invn, beta, bvec, out, gcnt);
    k_final      <<<1, 64, 0, stream>>>(gcnt, out, out_size);
}